// Round 9
// baseline (304.714 us; speedup 1.0000x reference)
//
#include <hip/hip_runtime.h>

#define NHEAD 32
#define LSEQ  2048
#define DIM   64
#define QBLK  64
#define KBLK  64
#define NTILE (LSEQ / KBLK)
#define KSPL  2
#define HTILE (NTILE / KSPL)

typedef float  f32x4  __attribute__((ext_vector_type(4)));
typedef __bf16 bf16x8 __attribute__((ext_vector_type(8)));
typedef unsigned short u16;

__device__ __forceinline__ u16 f2bf(float f) {
    return __builtin_bit_cast(u16, (__bf16)f);   // HW RNE convert
}
__device__ __forceinline__ void st4bf(u16* p, float4 v) {
    union { u16 h[4]; uint2 q; } pk;
    pk.h[0] = f2bf(v.x); pk.h[1] = f2bf(v.y);
    pk.h[2] = f2bf(v.z); pk.h[3] = f2bf(v.w);
    *(uint2*)p = pk.q;
}
__device__ __forceinline__ bf16x8 comb64(const u16* a, const u16* b) {
    union { uint2 q[2]; bf16x8 v; } u;
    u.q[0] = *(const uint2*)a;
    u.q[1] = *(const uint2*)b;
    return u.v;
}

// async global->LDS, 16B per lane (HW: wave-uniform LDS base + lane*16)
__device__ __forceinline__ void gl_lds16(const u16* g, u16* l) {
    __builtin_amdgcn_global_load_lds(
        (const __attribute__((address_space(1))) void*)g,
        (__attribute__((address_space(3))) void*)l, 16, 0, 0);
}

// stage drained + all waves synced
#define TILE_SYNC() asm volatile("s_waitcnt vmcnt(0)\n\ts_barrier" ::: "memory")
// plain barrier: safe when this wave's prior LDS reads were all consumed
// (compiler lgkm-waits before each MFMA use) and no VMEM ordering is needed
#define BAR_ONLY()  asm volatile("s_barrier" ::: "memory")

// 0.125 (1/sqrt(64)) * log2(e): softmax computed in exp2 domain
#define QSCALE 0.18033688011112042f
#define RESCALE_THR 8.0f

// ============================================================================
// Pre-pass: K -> bf16 tiles, V -> V^T bf16 tiles (gload_lds-linear + XOR-
// swizzled layout), PLUS the mask^2 loss term. (unchanged, proven r4-r8)
// ============================================================================
__global__ void prepack_kernel(const float* __restrict__ K,
                               const float* __restrict__ V,
                               const float* __restrict__ Msk,
                               u16* __restrict__ wsK, u16* __restrict__ wsV,
                               float* __restrict__ loss)
{
    __shared__ float sv[64][65];
    __shared__ float red2[4];
    const int b = blockIdx.x;          // head*NTILE + kb
    const int head = b >> 5, kb = b & 31;
    const int t = threadIdx.x;
    const size_t hoff = (size_t)head * LSEQ * DIM;
    const float* Kg = K + hoff + (size_t)(kb * KBLK) * DIM;
    const float* Vg = V + hoff + (size_t)(kb * KBLK) * DIM;
    u16* outK = wsK + (size_t)b * 4096;
    u16* outV = wsV + (size_t)b * 4096;

#pragma unroll
    for (int i = 0; i < 16; ++i) {
        const int e = t + 256 * i;
        sv[e >> 6][e & 63] = Vg[e];
    }
#pragma unroll
    for (int i = 0; i < 2; ++i) {
        const int c = t + 256 * i;
        const int r = c >> 3, q = c & 7;
        const int d0 = 8 * (q ^ (r & 7));
        float4 a  = *(const float4*)(Kg + r * DIM + d0);
        float4 bb = *(const float4*)(Kg + r * DIM + d0 + 4);
        union { u16 h[8]; uint4 u; } pk;
        pk.h[0]=f2bf(a.x);  pk.h[1]=f2bf(a.y);  pk.h[2]=f2bf(a.z);  pk.h[3]=f2bf(a.w);
        pk.h[4]=f2bf(bb.x); pk.h[5]=f2bf(bb.y); pk.h[6]=f2bf(bb.z); pk.h[7]=f2bf(bb.w);
        *(uint4*)(outK + c * 8) = pk.u;
    }
    __syncthreads();
#pragma unroll
    for (int i = 0; i < 2; ++i) {
        const int c = t + 256 * i;
        const int d = c >> 3, q = c & 7;
        const int cl = q ^ (d & 7);
        const int mp = cl >> 2, lq = cl & 3;
        union { u16 h[8]; uint4 u; } pk;
#pragma unroll
        for (int s = 0; s < 2; ++s) {
            const int k0 = 4 * (8 * mp + 4 * s + lq);
#pragma unroll
            for (int j = 0; j < 4; ++j)
                pk.h[4 * s + j] = f2bf(sv[k0 + j][d]);
        }
        *(uint4*)(outV + c * 8) = pk.u;
    }

    float s = 0.f;
    const float4* mq = (const float4*)(Msk + (size_t)b * 4096);
#pragma unroll
    for (int i = 0; i < 4; ++i) {
        float4 v = mq[t + 256 * i];
        s += v.x * v.x + v.y * v.y + v.z * v.z + v.w * v.w;
    }
#pragma unroll
    for (int off = 1; off <= 32; off <<= 1) s += __shfl_xor(s, off);
    if ((t & 63) == 0) red2[t >> 6] = s;
    __syncthreads();
    if (t == 0)
        atomicAdd(loss, 32.0f * (red2[0] + red2[1] + red2[2] + red2[3]));
}

// ============================================================================
// Split attention kernel: block = (head, qb, k-split). 2048 blocks -> 8
// blocks/CU -> 8 waves/SIMD (the TLP lever). Single-buffered 16KB LDS,
// 2 barriers/tile, r4's proven conflict-free body. Writes UNNORMALIZED
// partials (acc, m, l, la2, lam) in exp2 domain to ws.
// ============================================================================
__launch_bounds__(256, 8)
__global__ void attn_split_kernel(const float* __restrict__ Q,
                                  const u16* __restrict__ wsK,
                                  const u16* __restrict__ wsV,
                                  const float* __restrict__ Msk,
                                  float* __restrict__ wsO,
                                  float* __restrict__ wsS)
{
    __shared__ __align__(16) u16 lds_k[4096];   // 8KB K tile image
    __shared__ __align__(16) u16 lds_v[4096];   // 8KB V^T tile image

    const int t  = threadIdx.x;
    // bijective XCD-chunked swizzle: 2048 blocks, 8 XCDs, 256-block chunks
    // (4 heads per XCD chunk -> all q-blocks+splits of a head share an L2)
    const int wg   = ((int)blockIdx.x & 7) * 256 + ((int)blockIdx.x >> 3);
    const int head = wg >> 6;
    const int rem  = wg & 63;
    const int qb   = rem >> 1;
    const int sp   = rem & 1;
    const int qbase = qb * QBLK;
    const int w  = t >> 6;
    const int l  = t & 63;
    const int lr = l & 15;
    const int lq = l >> 4;
    const int x7 = lr & 7;

    const size_t hoff = (size_t)head * LSEQ * DIM;
    const int qg = qbase + 16 * w + lr;

    // ---- Q fragments, scale folded in (slots c = 32s + 8lq + j) ----
    bf16x8 qf[2];
#pragma unroll
    for (int s = 0; s < 2; ++s) {
        const float* src = Q + hoff + (size_t)qg * DIM + 32 * s + 8 * lq;
        float4 a = *(const float4*)(src);
        float4 b = *(const float4*)(src + 4);
        union { u16 h[8]; bf16x8 v; } u;
        u.h[0] = f2bf(a.x * QSCALE); u.h[1] = f2bf(a.y * QSCALE);
        u.h[2] = f2bf(a.z * QSCALE); u.h[3] = f2bf(a.w * QSCALE);
        u.h[4] = f2bf(b.x * QSCALE); u.h[5] = f2bf(b.y * QSCALE);
        u.h[6] = f2bf(b.z * QSCALE); u.h[7] = f2bf(b.w * QSCALE);
        qf[s] = u.v;
    }

    f32x4 acc[4];
#pragma unroll
    for (int dt = 0; dt < 4; ++dt) acc[dt] = (f32x4){0.f, 0.f, 0.f, 0.f};
    float mrun = -1e30f, lrun = 0.f, la2 = 0.f, lam = 0.f;

    const u16* srcK = wsK + (size_t)(head * NTILE) * 4096 + t * 8;
    const u16* srcV = wsV + (size_t)(head * NTILE) * 4096 + t * 8;

    const int kb0 = sp * HTILE;
    for (int kk = 0; kk < HTILE; ++kk) {
        const int kb = kb0 + kk;

        BAR_ONLY();   // all waves' reads of the previous tile are complete

        // ---- mask -> regs (issued OLDEST in vmcnt order) ----
        f32x4 mreg[4];
        {
            const float* mp_ = Msk + (size_t)qg * LSEQ + kb * KBLK + 4 * lq;
#pragma unroll
            for (int m = 0; m < 4; ++m)
                mreg[m] = *(const f32x4*)(mp_ + 16 * m);
        }
        // ---- stage tile kb into LDS (async, drained at TILE_SYNC) ----
        {
            const u16* gk = srcK + (size_t)kb * 4096;
            const u16* gv = srcV + (size_t)kb * 4096;
            gl_lds16(gk,        &lds_k[t * 8]);
            gl_lds16(gk + 2048, &lds_k[t * 8 + 2048]);
            gl_lds16(gv,        &lds_v[t * 8]);
            gl_lds16(gv + 2048, &lds_v[t * 8 + 2048]);
        }
        TILE_SYNC();

        // ---- S^T = K * Q^T : D col=q(=lr), row k = 16m + 4lq + r ----
        f32x4 S[4];
        __builtin_amdgcn_s_setprio(1);
#pragma unroll
        for (int m = 0; m < 4; ++m) {
            const u16* kro = &lds_k[(16 * m + lr) * 64];
            bf16x8 kf0 = *(const bf16x8*)(kro + ((lq ^ x7) << 3));
            bf16x8 kf1 = *(const bf16x8*)(kro + (((lq + 4) ^ x7) << 3));
            f32x4 z = (f32x4){0.f, 0.f, 0.f, 0.f};
            z = __builtin_amdgcn_mfma_f32_16x16x32_bf16(kf0, qf[0], z, 0, 0, 0);
            z = __builtin_amdgcn_mfma_f32_16x16x32_bf16(kf1, qf[1], z, 0, 0, 0);
            S[m] = z;
        }
        __builtin_amdgcn_s_setprio(0);

        // ---- defer-max online softmax (shfl-free fast path) ----
        float tm = fmaxf(fmaxf(fmaxf(S[0][0], S[0][1]), fmaxf(S[0][2], S[0][3])),
                         fmaxf(fmaxf(S[1][0], S[1][1]), fmaxf(S[1][2], S[1][3])));
        tm = fmaxf(tm, fmaxf(fmaxf(fmaxf(S[2][0], S[2][1]), fmaxf(S[2][2], S[2][3])),
                             fmaxf(fmaxf(S[3][0], S[3][1]), fmaxf(S[3][2], S[3][3]))));
        if (!__all(tm - mrun <= RESCALE_THR)) {      // wave-uniform branch
            tm = fmaxf(tm, __shfl_xor(tm, 16));
            tm = fmaxf(tm, __shfl_xor(tm, 32));
            const float mn = fmaxf(mrun, tm);
            const float al = __builtin_amdgcn_exp2f(mrun - mn);
            mrun = mn;                                // stays quad-uniform
            lrun *= al; la2 *= al * al; lam *= al;
#pragma unroll
            for (int dt = 0; dt < 4; ++dt) acc[dt] *= al;
        }

        float psum = 0.f, pp2 = 0.f, ppm = 0.f;
        u16 pb[16];
#pragma unroll
        for (int m = 0; m < 4; ++m) {
#pragma unroll
            for (int r = 0; r < 4; ++r) {
                float p = __builtin_amdgcn_exp2f(S[m][r] - mrun);
                psum += p;
                pp2  += p * p;
                ppm  += p * mreg[m][r];
                pb[4 * m + r] = f2bf(p);
            }
        }
        lrun += psum; la2 += pp2; lam += ppm;

        // ---- O^T += V^T * P ----
        bf16x8 pf0, pf1;
        {
            union { u16 h[8]; bf16x8 v; } u;
            u.h[0] = pb[0]; u.h[1] = pb[1]; u.h[2] = pb[2]; u.h[3] = pb[3];
            u.h[4] = pb[4]; u.h[5] = pb[5]; u.h[6] = pb[6]; u.h[7] = pb[7];
            pf0 = u.v;
        }
        {
            union { u16 h[8]; bf16x8 v; } u;
            u.h[0] = pb[8];  u.h[1] = pb[9];  u.h[2] = pb[10]; u.h[3] = pb[11];
            u.h[4] = pb[12]; u.h[5] = pb[13]; u.h[6] = pb[14]; u.h[7] = pb[15];
            pf1 = u.v;
        }
        __builtin_amdgcn_s_setprio(1);
#pragma unroll
        for (int dt = 0; dt < 4; ++dt) {
            const u16* vro = &lds_v[(16 * dt + lr) * 64];
            bf16x8 vfa = *(const bf16x8*)(vro + ((lq ^ x7) << 3));
            bf16x8 vfb = *(const bf16x8*)(vro + (((4 + lq) ^ x7) << 3));
            acc[dt] = __builtin_amdgcn_mfma_f32_16x16x32_bf16(vfa, pf0, acc[dt], 0, 0, 0);
            acc[dt] = __builtin_amdgcn_mfma_f32_16x16x32_bf16(vfb, pf1, acc[dt], 0, 0, 0);
        }
        __builtin_amdgcn_s_setprio(0);
    }

    // ---- reduce row partials across the 4 k-groups (quad lanes xor 16,32) ----
#pragma unroll
    for (int off = 16; off <= 32; off <<= 1) {
        lrun += __shfl_xor(lrun, off);
        la2  += __shfl_xor(la2,  off);
        lam  += __shfl_xor(lam,  off);
    }

    // ---- write UNNORMALIZED partials ----
    float* po = wsO + (size_t)sp * NHEAD * LSEQ * DIM;
#pragma unroll
    for (int dt = 0; dt < 4; ++dt) {
        float4 o;
        o.x = acc[dt][0]; o.y = acc[dt][1]; o.z = acc[dt][2]; o.w = acc[dt][3];
        *(float4*)(po + hoff + (size_t)qg * DIM + 16 * dt + 4 * lq) = o;
    }
    if (l < 16) {   // one lane per q-row (lq==0): {m, l, la2, lam}
        float4 sc;
        sc.x = mrun; sc.y = lrun; sc.z = la2; sc.w = lam;
        *(float4*)(wsS + ((size_t)sp * NHEAD * LSEQ + (size_t)head * LSEQ + qg) * 4) = sc;
    }
}

// ============================================================================
// Combine the 2 splits: renormalize O, accumulate the loss cross-terms.
// Block = (head, qb); thread t -> row t>>2, 16 d's at (t&3)*16.
// ============================================================================
__global__ void combine_kernel(const float* __restrict__ wsO,
                               const float* __restrict__ wsS,
                               float* __restrict__ out,
                               float* __restrict__ loss)
{
    __shared__ float red[4];
    const int b = blockIdx.x;
    const int head = b >> 5, qb = b & 31;
    const int t = threadIdx.x;
    const int row = t >> 2;
    const int dq  = (t & 3) * 16;
    const int q = qb * QBLK + row;
    const size_t ro = (size_t)head * LSEQ + q;

    float4 s0 = *(const float4*)(wsS + ro * 4);
    float4 s1 = *(const float4*)(wsS + ((size_t)NHEAD * LSEQ + ro) * 4);
    const float m  = fmaxf(s0.x, s1.x);
    const float e0 = __builtin_amdgcn_exp2f(s0.x - m);
    const float e1 = __builtin_amdgcn_exp2f(s1.x - m);
    const float lsum = e0 * s0.y + e1 * s1.y;
    const float inv  = 1.0f / lsum;

    const float* a0 = wsO + ro * DIM + dq;
    const float* a1 = wsO + (size_t)NHEAD * LSEQ * DIM + ro * DIM + dq;
    float* op = out + ro * DIM + dq;
#pragma unroll
    for (int i = 0; i < 4; ++i) {
        float4 x0 = *(const float4*)(a0 + 4 * i);
        float4 x1 = *(const float4*)(a1 + 4 * i);
        float4 o;
        o.x = (e0 * x0.x + e1 * x1.x) * inv;
        o.y = (e0 * x0.y + e1 * x1.y) * inv;
        o.z = (e0 * x0.z + e1 * x1.z) * inv;
        o.w = (e0 * x0.w + e1 * x1.w) * inv;
        *(float4*)(op + 4 * i) = o;
    }

    float part = 0.f;
    if ((t & 3) == 0) {
        const float la2 = e0 * e0 * s0.z + e1 * e1 * s1.z;
        const float lam = e0 * s0.w + e1 * s1.w;
        part = la2 * inv * inv - 2.0f * lam * inv;
    }
#pragma unroll
    for (int off = 1; off <= 32; off <<= 1) part += __shfl_xor(part, off);
    if ((t & 63) == 0) red[t >> 6] = part;
    __syncthreads();
    if (t == 0)
        atomicAdd(loss, red[0] + red[1] + red[2] + red[3]);
}

// ============================================================================
// Fallback (proven r3 kernel) + standalone masksq if workspace too small.
// ============================================================================
__global__ void masksq_kernel(const float* __restrict__ Msk, float* __restrict__ loss)
{
    __shared__ float red[4];
    float s = 0.f;
    const size_t n4 = (size_t)LSEQ * LSEQ / 4;
    for (size_t i = (size_t)blockIdx.x * blockDim.x + threadIdx.x; i < n4;
         i += (size_t)gridDim.x * blockDim.x) {
        float4 v = ((const float4*)Msk)[i];
        s += v.x * v.x + v.y * v.y + v.z * v.z + v.w * v.w;
    }
#pragma unroll
    for (int off = 1; off <= 32; off <<= 1) s += __shfl_xor(s, off);
    if ((threadIdx.x & 63) == 0) red[threadIdx.x >> 6] = s;
    __syncthreads();
    if (threadIdx.x == 0) {
        float tot = red[0] + red[1] + red[2] + red[3];
        atomicAdd(loss, 32.0f * tot);
    }
}

__launch_bounds__(256, 4)
__global__ void attn_fallback_kernel(const float* __restrict__ Q,
                                     const float* __restrict__ K,
                                     const float* __restrict__ V,
                                     const float* __restrict__ Msk,
                                     float* __restrict__ out,
                                     float* __restrict__ loss)
{
    __shared__ __align__(16) u16 lds_k[64][72];
    __shared__ __align__(16) u16 lds_v[64][68];

    const int t  = threadIdx.x;
    const int wg   = ((int)blockIdx.x & 7) * 128 + ((int)blockIdx.x >> 3);
    const int head = wg >> 5;
    const int qb   = wg & 31;
    const int qbase = qb * QBLK;
    const int w  = t >> 6;
    const int l  = t & 63;
    const int lr = l & 15;
    const int lq = l >> 4;

    const size_t hoff = (size_t)head * LSEQ * DIM;
    const int qg = qbase + 16 * w + lr;

    bf16x8 qf[2];
#pragma unroll
    for (int s = 0; s < 2; ++s) {
        const float* src = Q + hoff + (size_t)qg * DIM + 32 * s + 8 * lq;
        float4 a = *(const float4*)(src);
        float4 b = *(const float4*)(src + 4);
        union { u16 h[8]; bf16x8 v; } u;
        u.h[0] = f2bf(a.x * QSCALE); u.h[1] = f2bf(a.y * QSCALE);
        u.h[2] = f2bf(a.z * QSCALE); u.h[3] = f2bf(a.w * QSCALE);
        u.h[4] = f2bf(b.x * QSCALE); u.h[5] = f2bf(b.y * QSCALE);
        u.h[6] = f2bf(b.z * QSCALE); u.h[7] = f2bf(b.w * QSCALE);
        qf[s] = u.v;
    }

    f32x4 acc[4];
#pragma unroll
    for (int dt = 0; dt < 4; ++dt) acc[dt] = (f32x4){0.f, 0.f, 0.f, 0.f};
    float mrun = -1e30f, lrun = 0.f, la2 = 0.f, lam = 0.f;

    for (int kb = 0; kb < NTILE; ++kb) {
        const int kbase = kb * KBLK;
        __syncthreads();
        f32x4 mreg[4];
        {
            const float* mp_ = Msk + (size_t)qg * LSEQ + kbase + 4 * lq;
#pragma unroll
            for (int m = 0; m < 4; ++m)
                mreg[m] = *(const f32x4*)(mp_ + 16 * m);
        }
        {
            const float* Kg = K + hoff + (size_t)kbase * DIM;
            const float* Vg = V + hoff + (size_t)kbase * DIM;
#pragma unroll
            for (int i = 0; i < 4; ++i) {
                const int id = t + 256 * i;
                const int r = id >> 4, c = (id & 15) * 4;
                float4 kv = *(const float4*)(Kg + r * DIM + c);
                float4 vv = *(const float4*)(Vg + r * DIM + c);
                st4bf(&lds_k[r][c], kv);
                lds_v[c + 0][r] = f2bf(vv.x);
                lds_v[c + 1][r] = f2bf(vv.y);
                lds_v[c + 2][r] = f2bf(vv.z);
                lds_v[c + 3][r] = f2bf(vv.w);
            }
        }
        __syncthreads();

        f32x4 S[4];
#pragma unroll
        for (int m = 0; m < 4; ++m) {
            bf16x8 kf0 = *(const bf16x8*)&lds_k[16 * m + lr][8 * lq];
            bf16x8 kf1 = *(const bf16x8*)&lds_k[16 * m + lr][32 + 8 * lq];
            f32x4 z = (f32x4){0.f, 0.f, 0.f, 0.f};
            z = __builtin_amdgcn_mfma_f32_16x16x32_bf16(kf0, qf[0], z, 0, 0, 0);
            z = __builtin_amdgcn_mfma_f32_16x16x32_bf16(kf1, qf[1], z, 0, 0, 0);
            S[m] = z;
        }

        float tm = fmaxf(fmaxf(fmaxf(S[0][0], S[0][1]), fmaxf(S[0][2], S[0][3])),
                         fmaxf(fmaxf(S[1][0], S[1][1]), fmaxf(S[1][2], S[1][3])));
        tm = fmaxf(tm, fmaxf(fmaxf(fmaxf(S[2][0], S[2][1]), fmaxf(S[2][2], S[2][3])),
                             fmaxf(fmaxf(S[3][0], S[3][1]), fmaxf(S[3][2], S[3][3]))));
        tm = fmaxf(tm, __shfl_xor(tm, 16));
        tm = fmaxf(tm, __shfl_xor(tm, 32));
        if (!__all(tm - mrun <= RESCALE_THR)) {
            const float mn = fmaxf(mrun, tm);
            const float al = __builtin_amdgcn_exp2f(mrun - mn);
            mrun = mn;
            lrun *= al; la2 *= al * al; lam *= al;
#pragma unroll
            for (int dt = 0; dt < 4; ++dt) acc[dt] *= al;
        }

        float psum = 0.f, pp2 = 0.f, ppm = 0.f;
        u16 pb[16];
#pragma unroll
        for (int m = 0; m < 4; ++m) {
#pragma unroll
            for (int r = 0; r < 4; ++r) {
                float p = __builtin_amdgcn_exp2f(S[m][r] - mrun);
                psum += p;
                pp2  += p * p;
                ppm  += p * mreg[m][r];
                pb[4 * m + r] = f2bf(p);
            }
        }
        lrun += psum; la2 += pp2; lam += ppm;

        bf16x8 pf[2];
#pragma unroll
        for (int mp = 0; mp < 2; ++mp) {
            union { u16 h[8]; bf16x8 v; } u;
#pragma unroll
            for (int j = 0; j < 4; ++j) { u.h[j] = pb[8 * mp + j]; u.h[4 + j] = pb[8 * mp + 4 + j]; }
            pf[mp] = u.v;
        }
#pragma unroll
        for (int dt = 0; dt < 4; ++dt) {
#pragma unroll
            for (int mp = 0; mp < 2; ++mp) {
                bf16x8 vf = comb64(&lds_v[16 * dt + lr][32 * mp + 4 * lq],
                                   &lds_v[16 * dt + lr][32 * mp + 16 + 4 * lq]);
                acc[dt] = __builtin_amdgcn_mfma_f32_16x16x32_bf16(vf, pf[mp], acc[dt], 0, 0, 0);
            }
        }
    }

#pragma unroll
    for (int off = 16; off <= 32; off <<= 1) {
        lrun += __shfl_xor(lrun, off);
        la2  += __shfl_xor(la2,  off);
        lam  += __shfl_xor(lam,  off);
    }
    const float inv = 1.0f / lrun;
#pragma unroll
    for (int dt = 0; dt < 4; ++dt) {
        float4 o;
        o.x = acc[dt][0] * inv; o.y = acc[dt][1] * inv;
        o.z = acc[dt][2] * inv; o.w = acc[dt][3] * inv;
        *(float4*)(out + hoff + (size_t)qg * DIM + 16 * dt + 4 * lq) = o;
    }
    float part = la2 * inv * inv - 2.0f * lam * inv;
    part = (l < 16) ? part : 0.f;
#pragma unroll
    for (int off = 1; off <= 8; off <<= 1) part += __shfl_xor(part, off);
    if (l == 0) atomicAdd(loss, part);
}

extern "C" void kernel_launch(void* const* d_in, const int* in_sizes, int n_in,
                              void* d_out, int out_size, void* d_ws, size_t ws_size,
                              hipStream_t stream)
{
    const float* Q   = (const float*)d_in[0];
    const float* K   = (const float*)d_in[1];
    const float* V   = (const float*)d_in[2];
    const float* Msk = (const float*)d_in[3];
    float* out  = (float*)d_out;
    float* loss = out + (size_t)NHEAD * LSEQ * DIM;  // element 4194304

    hipMemsetAsync(loss, 0, sizeof(float), stream);

    const size_t packB = (size_t)2 * NHEAD * NTILE * 4096 * sizeof(u16);        // 16 MB
    const size_t oB    = (size_t)KSPL * NHEAD * LSEQ * DIM * sizeof(float);     // 32 MB
    const size_t sB    = (size_t)KSPL * NHEAD * LSEQ * 4 * sizeof(float);       // 2 MB
    const size_t need  = packB + oB + sB;                                       // ~50 MB

    if (d_ws && ws_size >= need) {
        u16* wsK  = (u16*)d_ws;
        u16* wsV  = wsK + (size_t)NHEAD * NTILE * 4096;
        float* wsO = (float*)((char*)d_ws + packB);
        float* wsS = (float*)((char*)d_ws + packB + oB);
        prepack_kernel<<<NHEAD * NTILE, 256, 0, stream>>>(K, V, Msk, wsK, wsV, loss);
        attn_split_kernel<<<NHEAD * (LSEQ / QBLK) * KSPL, 256, 0, stream>>>(
            Q, wsK, wsV, Msk, wsO, wsS);
        combine_kernel<<<NHEAD * (LSEQ / QBLK), 256, 0, stream>>>(wsO, wsS, out, loss);
    } else {
        masksq_kernel<<<256, 256, 0, stream>>>(Msk, loss);
        attn_fallback_kernel<<<NHEAD * (LSEQ / QBLK), 256, 0, stream>>>(Q, K, V, Msk, out, loss);
    }
}

// Round 10
// 191.004 us; speedup vs baseline: 1.5953x; 1.5953x over previous
//
#include <hip/hip_runtime.h>

#define NHEAD 32
#define LSEQ  2048
#define DIM   64
#define QBLK  64
#define KBLK  64
#define NTILE (LSEQ / KBLK)
#define KSPL  2
#define HTILE (NTILE / KSPL)

typedef float  f32x4  __attribute__((ext_vector_type(4)));
typedef __bf16 bf16x8 __attribute__((ext_vector_type(8)));
typedef unsigned short u16;

__device__ __forceinline__ u16 f2bf(float f) {
    return __builtin_bit_cast(u16, (__bf16)f);   // HW RNE convert
}
__device__ __forceinline__ void st4bf(u16* p, float4 v) {
    union { u16 h[4]; uint2 q; } pk;
    pk.h[0] = f2bf(v.x); pk.h[1] = f2bf(v.y);
    pk.h[2] = f2bf(v.z); pk.h[3] = f2bf(v.w);
    *(uint2*)p = pk.q;
}
__device__ __forceinline__ bf16x8 comb64(const u16* a, const u16* b) {
    union { uint2 q[2]; bf16x8 v; } u;
    u.q[0] = *(const uint2*)a;
    u.q[1] = *(const uint2*)b;
    return u.v;
}

// async global->LDS, 16B per lane (HW: wave-uniform LDS base + lane*16)
__device__ __forceinline__ void gl_lds16(const u16* g, u16* l) {
    __builtin_amdgcn_global_load_lds(
        (const __attribute__((address_space(1))) void*)g,
        (__attribute__((address_space(3))) void*)l, 16, 0, 0);
}

// stage drained + all waves synced
#define TILE_SYNC() asm volatile("s_waitcnt vmcnt(0)\n\ts_barrier" ::: "memory")
// plain barrier: safe because every wave's prior LDS reads were consumed
// (compiler lgkm-waits before each MFMA use) before it arrives here
#define BAR_ONLY()  asm volatile("s_barrier" ::: "memory")

// 0.125 (1/sqrt(64)) * log2(e): softmax computed in exp2 domain
#define QSCALE 0.18033688011112042f
#define RESCALE_THR 8.0f

// ============================================================================
// Pre-pass: K -> bf16 tiles, V -> V^T bf16 tiles (gload_lds-linear + XOR-
// swizzled layout), PLUS the mask^2 loss term. (unchanged, proven r4-r9)
// ============================================================================
__global__ void prepack_kernel(const float* __restrict__ K,
                               const float* __restrict__ V,
                               const float* __restrict__ Msk,
                               u16* __restrict__ wsK, u16* __restrict__ wsV,
                               float* __restrict__ loss)
{
    __shared__ float sv[64][65];
    __shared__ float red2[4];
    const int b = blockIdx.x;          // head*NTILE + kb
    const int head = b >> 5, kb = b & 31;
    const int t = threadIdx.x;
    const size_t hoff = (size_t)head * LSEQ * DIM;
    const float* Kg = K + hoff + (size_t)(kb * KBLK) * DIM;
    const float* Vg = V + hoff + (size_t)(kb * KBLK) * DIM;
    u16* outK = wsK + (size_t)b * 4096;
    u16* outV = wsV + (size_t)b * 4096;

#pragma unroll
    for (int i = 0; i < 16; ++i) {
        const int e = t + 256 * i;
        sv[e >> 6][e & 63] = Vg[e];
    }
#pragma unroll
    for (int i = 0; i < 2; ++i) {
        const int c = t + 256 * i;
        const int r = c >> 3, q = c & 7;
        const int d0 = 8 * (q ^ (r & 7));
        float4 a  = *(const float4*)(Kg + r * DIM + d0);
        float4 bb = *(const float4*)(Kg + r * DIM + d0 + 4);
        union { u16 h[8]; uint4 u; } pk;
        pk.h[0]=f2bf(a.x);  pk.h[1]=f2bf(a.y);  pk.h[2]=f2bf(a.z);  pk.h[3]=f2bf(a.w);
        pk.h[4]=f2bf(bb.x); pk.h[5]=f2bf(bb.y); pk.h[6]=f2bf(bb.z); pk.h[7]=f2bf(bb.w);
        *(uint4*)(outK + c * 8) = pk.u;
    }
    __syncthreads();
#pragma unroll
    for (int i = 0; i < 2; ++i) {
        const int c = t + 256 * i;
        const int d = c >> 3, q = c & 7;
        const int cl = q ^ (d & 7);
        const int mp = cl >> 2, lq = cl & 3;
        union { u16 h[8]; uint4 u; } pk;
#pragma unroll
        for (int s = 0; s < 2; ++s) {
            const int k0 = 4 * (8 * mp + 4 * s + lq);
#pragma unroll
            for (int j = 0; j < 4; ++j)
                pk.h[4 * s + j] = f2bf(sv[k0 + j][d]);
        }
        *(uint4*)(outV + c * 8) = pk.u;
    }

    float s = 0.f;
    const float4* mq = (const float4*)(Msk + (size_t)b * 4096);
#pragma unroll
    for (int i = 0; i < 4; ++i) {
        float4 v = mq[t + 256 * i];
        s += v.x * v.x + v.y * v.y + v.z * v.z + v.w * v.w;
    }
#pragma unroll
    for (int off = 1; off <= 32; off <<= 1) s += __shfl_xor(s, off);
    if ((t & 63) == 0) red2[t >> 6] = s;
    __syncthreads();
    if (t == 0)
        atomicAdd(loss, 32.0f * (red2[0] + red2[1] + red2[2] + red2[3]));
}

// ============================================================================
// Split attention kernel: block = (head, qb, k-split). 2048 blocks; 6
// blocks/CU resident -> 6 waves/SIMD (1.5x the r4-r7 TLP).
// __launch_bounds__(256,6): VGPR cap 85 >= ~64-75 natural need -> NO SPILLS
// (r9's (256,8) cap of 64 caused 1.1GB of scratch traffic and confounded
// the TLP test). Single-buffered 16KB LDS, r4's proven conflict-free body.
// Writes UNNORMALIZED partials (acc, m, l, la2, lam) in exp2 domain to ws.
// ============================================================================
__launch_bounds__(256, 6)
__global__ void attn_split_kernel(const float* __restrict__ Q,
                                  const u16* __restrict__ wsK,
                                  const u16* __restrict__ wsV,
                                  const float* __restrict__ Msk,
                                  float* __restrict__ wsO,
                                  float* __restrict__ wsS)
{
    __shared__ __align__(16) u16 lds_k[4096];   // 8KB K tile image
    __shared__ __align__(16) u16 lds_v[4096];   // 8KB V^T tile image

    const int t  = threadIdx.x;
    // bijective XCD-chunked swizzle: 2048 blocks, 8 XCDs, 256-block chunks
    const int wg   = ((int)blockIdx.x & 7) * 256 + ((int)blockIdx.x >> 3);
    const int head = wg >> 6;
    const int rem  = wg & 63;
    const int qb   = rem >> 1;
    const int sp   = rem & 1;
    const int qbase = qb * QBLK;
    const int w  = t >> 6;
    const int l  = t & 63;
    const int lr = l & 15;
    const int lq = l >> 4;
    const int x7 = lr & 7;

    const size_t hoff = (size_t)head * LSEQ * DIM;
    const int qg = qbase + 16 * w + lr;

    // ---- Q fragments, scale folded in (slots c = 32s + 8lq + j) ----
    bf16x8 qf[2];
#pragma unroll
    for (int s = 0; s < 2; ++s) {
        const float* src = Q + hoff + (size_t)qg * DIM + 32 * s + 8 * lq;
        float4 a = *(const float4*)(src);
        float4 b = *(const float4*)(src + 4);
        union { u16 h[8]; bf16x8 v; } u;
        u.h[0] = f2bf(a.x * QSCALE); u.h[1] = f2bf(a.y * QSCALE);
        u.h[2] = f2bf(a.z * QSCALE); u.h[3] = f2bf(a.w * QSCALE);
        u.h[4] = f2bf(b.x * QSCALE); u.h[5] = f2bf(b.y * QSCALE);
        u.h[6] = f2bf(b.z * QSCALE); u.h[7] = f2bf(b.w * QSCALE);
        qf[s] = u.v;
    }

    f32x4 acc[4];
#pragma unroll
    for (int dt = 0; dt < 4; ++dt) acc[dt] = (f32x4){0.f, 0.f, 0.f, 0.f};
    float mrun = -1e30f, lrun = 0.f, la2 = 0.f, lam = 0.f;

    const u16* srcK = wsK + (size_t)(head * NTILE) * 4096 + t * 8;
    const u16* srcV = wsV + (size_t)(head * NTILE) * 4096 + t * 8;

    const int kb0 = sp * HTILE;
    for (int kk = 0; kk < HTILE; ++kk) {
        const int kb = kb0 + kk;

        BAR_ONLY();   // all waves' reads of the previous tile are complete

        // ---- mask -> regs (issued OLDEST in vmcnt order) ----
        f32x4 mreg[4];
        {
            const float* mp_ = Msk + (size_t)qg * LSEQ + kb * KBLK + 4 * lq;
#pragma unroll
            for (int m = 0; m < 4; ++m)
                mreg[m] = *(const f32x4*)(mp_ + 16 * m);
        }
        // ---- stage tile kb into LDS (async, drained at TILE_SYNC) ----
        {
            const u16* gk = srcK + (size_t)kb * 4096;
            const u16* gv = srcV + (size_t)kb * 4096;
            gl_lds16(gk,        &lds_k[t * 8]);
            gl_lds16(gk + 2048, &lds_k[t * 8 + 2048]);
            gl_lds16(gv,        &lds_v[t * 8]);
            gl_lds16(gv + 2048, &lds_v[t * 8 + 2048]);
        }
        TILE_SYNC();

        // ---- S^T = K * Q^T : D col=q(=lr), row k = 16m + 4lq + r ----
        f32x4 S[4];
        __builtin_amdgcn_s_setprio(1);
#pragma unroll
        for (int m = 0; m < 4; ++m) {
            const u16* kro = &lds_k[(16 * m + lr) * 64];
            bf16x8 kf0 = *(const bf16x8*)(kro + ((lq ^ x7) << 3));
            bf16x8 kf1 = *(const bf16x8*)(kro + (((lq + 4) ^ x7) << 3));
            f32x4 z = (f32x4){0.f, 0.f, 0.f, 0.f};
            z = __builtin_amdgcn_mfma_f32_16x16x32_bf16(kf0, qf[0], z, 0, 0, 0);
            z = __builtin_amdgcn_mfma_f32_16x16x32_bf16(kf1, qf[1], z, 0, 0, 0);
            S[m] = z;
        }
        __builtin_amdgcn_s_setprio(0);

        // ---- defer-max online softmax (shfl-free fast path) ----
        float tm = fmaxf(fmaxf(fmaxf(S[0][0], S[0][1]), fmaxf(S[0][2], S[0][3])),
                         fmaxf(fmaxf(S[1][0], S[1][1]), fmaxf(S[1][2], S[1][3])));
        tm = fmaxf(tm, fmaxf(fmaxf(fmaxf(S[2][0], S[2][1]), fmaxf(S[2][2], S[2][3])),
                             fmaxf(fmaxf(S[3][0], S[3][1]), fmaxf(S[3][2], S[3][3]))));
        if (!__all(tm - mrun <= RESCALE_THR)) {      // wave-uniform branch
            tm = fmaxf(tm, __shfl_xor(tm, 16));
            tm = fmaxf(tm, __shfl_xor(tm, 32));
            const float mn = fmaxf(mrun, tm);
            const float al = __builtin_amdgcn_exp2f(mrun - mn);
            mrun = mn;                                // stays quad-uniform
            lrun *= al; la2 *= al * al; lam *= al;
#pragma unroll
            for (int dt = 0; dt < 4; ++dt) acc[dt] *= al;
        }

        float psum = 0.f, pp2 = 0.f, ppm = 0.f;
        u16 pb[16];
#pragma unroll
        for (int m = 0; m < 4; ++m) {
#pragma unroll
            for (int r = 0; r < 4; ++r) {
                float p = __builtin_amdgcn_exp2f(S[m][r] - mrun);
                psum += p;
                pp2  += p * p;
                ppm  += p * mreg[m][r];
                pb[4 * m + r] = f2bf(p);
            }
        }
        lrun += psum; la2 += pp2; lam += ppm;

        // ---- O^T += V^T * P ----
        bf16x8 pf0, pf1;
        {
            union { u16 h[8]; bf16x8 v; } u;
            u.h[0] = pb[0]; u.h[1] = pb[1]; u.h[2] = pb[2]; u.h[3] = pb[3];
            u.h[4] = pb[4]; u.h[5] = pb[5]; u.h[6] = pb[6]; u.h[7] = pb[7];
            pf0 = u.v;
        }
        {
            union { u16 h[8]; bf16x8 v; } u;
            u.h[0] = pb[8];  u.h[1] = pb[9];  u.h[2] = pb[10]; u.h[3] = pb[11];
            u.h[4] = pb[12]; u.h[5] = pb[13]; u.h[6] = pb[14]; u.h[7] = pb[15];
            pf1 = u.v;
        }
        __builtin_amdgcn_s_setprio(1);
#pragma unroll
        for (int dt = 0; dt < 4; ++dt) {
            const u16* vro = &lds_v[(16 * dt + lr) * 64];
            bf16x8 vfa = *(const bf16x8*)(vro + ((lq ^ x7) << 3));
            bf16x8 vfb = *(const bf16x8*)(vro + (((4 + lq) ^ x7) << 3));
            acc[dt] = __builtin_amdgcn_mfma_f32_16x16x32_bf16(vfa, pf0, acc[dt], 0, 0, 0);
            acc[dt] = __builtin_amdgcn_mfma_f32_16x16x32_bf16(vfb, pf1, acc[dt], 0, 0, 0);
        }
        __builtin_amdgcn_s_setprio(0);
    }

    // ---- reduce row partials across the 4 k-groups (quad lanes xor 16,32) ----
#pragma unroll
    for (int off = 16; off <= 32; off <<= 1) {
        lrun += __shfl_xor(lrun, off);
        la2  += __shfl_xor(la2,  off);
        lam  += __shfl_xor(lam,  off);
    }

    // ---- write UNNORMALIZED partials ----
    float* po = wsO + (size_t)sp * NHEAD * LSEQ * DIM;
#pragma unroll
    for (int dt = 0; dt < 4; ++dt) {
        float4 o;
        o.x = acc[dt][0]; o.y = acc[dt][1]; o.z = acc[dt][2]; o.w = acc[dt][3];
        *(float4*)(po + hoff + (size_t)qg * DIM + 16 * dt + 4 * lq) = o;
    }
    if (l < 16) {   // one lane per q-row (lq==0): {m, l, la2, lam}
        float4 sc;
        sc.x = mrun; sc.y = lrun; sc.z = la2; sc.w = lam;
        *(float4*)(wsS + ((size_t)sp * NHEAD * LSEQ + (size_t)head * LSEQ + qg) * 4) = sc;
    }
}

// ============================================================================
// Combine the 2 splits: renormalize O, accumulate the loss cross-terms.
// ============================================================================
__global__ void combine_kernel(const float* __restrict__ wsO,
                               const float* __restrict__ wsS,
                               float* __restrict__ out,
                               float* __restrict__ loss)
{
    __shared__ float red[4];
    const int b = blockIdx.x;
    const int head = b >> 5, qb = b & 31;
    const int t = threadIdx.x;
    const int row = t >> 2;
    const int dq  = (t & 3) * 16;
    const int q = qb * QBLK + row;
    const size_t ro = (size_t)head * LSEQ + q;

    float4 s0 = *(const float4*)(wsS + ro * 4);
    float4 s1 = *(const float4*)(wsS + ((size_t)NHEAD * LSEQ + ro) * 4);
    const float m  = fmaxf(s0.x, s1.x);
    const float e0 = __builtin_amdgcn_exp2f(s0.x - m);
    const float e1 = __builtin_amdgcn_exp2f(s1.x - m);
    const float lsum = e0 * s0.y + e1 * s1.y;
    const float inv  = 1.0f / lsum;

    const float* a0 = wsO + ro * DIM + dq;
    const float* a1 = wsO + (size_t)NHEAD * LSEQ * DIM + ro * DIM + dq;
    float* op = out + ro * DIM + dq;
#pragma unroll
    for (int i = 0; i < 4; ++i) {
        float4 x0 = *(const float4*)(a0 + 4 * i);
        float4 x1 = *(const float4*)(a1 + 4 * i);
        float4 o;
        o.x = (e0 * x0.x + e1 * x1.x) * inv;
        o.y = (e0 * x0.y + e1 * x1.y) * inv;
        o.z = (e0 * x0.z + e1 * x1.z) * inv;
        o.w = (e0 * x0.w + e1 * x1.w) * inv;
        *(float4*)(op + 4 * i) = o;
    }

    float part = 0.f;
    if ((t & 3) == 0) {
        const float la2 = e0 * e0 * s0.z + e1 * e1 * s1.z;
        const float lam = e0 * s0.w + e1 * s1.w;
        part = la2 * inv * inv - 2.0f * lam * inv;
    }
#pragma unroll
    for (int off = 1; off <= 32; off <<= 1) part += __shfl_xor(part, off);
    if ((t & 63) == 0) red[t >> 6] = part;
    __syncthreads();
    if (t == 0)
        atomicAdd(loss, red[0] + red[1] + red[2] + red[3]);
}

// ============================================================================
// Fallback (proven r3 kernel) + standalone masksq if workspace too small.
// ============================================================================
__global__ void masksq_kernel(const float* __restrict__ Msk, float* __restrict__ loss)
{
    __shared__ float red[4];
    float s = 0.f;
    const size_t n4 = (size_t)LSEQ * LSEQ / 4;
    for (size_t i = (size_t)blockIdx.x * blockDim.x + threadIdx.x; i < n4;
         i += (size_t)gridDim.x * blockDim.x) {
        float4 v = ((const float4*)Msk)[i];
        s += v.x * v.x + v.y * v.y + v.z * v.z + v.w * v.w;
    }
#pragma unroll
    for (int off = 1; off <= 32; off <<= 1) s += __shfl_xor(s, off);
    if ((threadIdx.x & 63) == 0) red[threadIdx.x >> 6] = s;
    __syncthreads();
    if (threadIdx.x == 0) {
        float tot = red[0] + red[1] + red[2] + red[3];
        atomicAdd(loss, 32.0f * tot);
    }
}

__launch_bounds__(256, 4)
__global__ void attn_fallback_kernel(const float* __restrict__ Q,
                                     const float* __restrict__ K,
                                     const float* __restrict__ V,
                                     const float* __restrict__ Msk,
                                     float* __restrict__ out,
                                     float* __restrict__ loss)
{
    __shared__ __align__(16) u16 lds_k[64][72];
    __shared__ __align__(16) u16 lds_v[64][68];

    const int t  = threadIdx.x;
    const int wg   = ((int)blockIdx.x & 7) * 128 + ((int)blockIdx.x >> 3);
    const int head = wg >> 5;
    const int qb   = wg & 31;
    const int qbase = qb * QBLK;
    const int w  = t >> 6;
    const int l  = t & 63;
    const int lr = l & 15;
    const int lq = l >> 4;

    const size_t hoff = (size_t)head * LSEQ * DIM;
    const int qg = qbase + 16 * w + lr;

    bf16x8 qf[2];
#pragma unroll
    for (int s = 0; s < 2; ++s) {
        const float* src = Q + hoff + (size_t)qg * DIM + 32 * s + 8 * lq;
        float4 a = *(const float4*)(src);
        float4 b = *(const float4*)(src + 4);
        union { u16 h[8]; bf16x8 v; } u;
        u.h[0] = f2bf(a.x * QSCALE); u.h[1] = f2bf(a.y * QSCALE);
        u.h[2] = f2bf(a.z * QSCALE); u.h[3] = f2bf(a.w * QSCALE);
        u.h[4] = f2bf(b.x * QSCALE); u.h[5] = f2bf(b.y * QSCALE);
        u.h[6] = f2bf(b.z * QSCALE); u.h[7] = f2bf(b.w * QSCALE);
        qf[s] = u.v;
    }

    f32x4 acc[4];
#pragma unroll
    for (int dt = 0; dt < 4; ++dt) acc[dt] = (f32x4){0.f, 0.f, 0.f, 0.f};
    float mrun = -1e30f, lrun = 0.f, la2 = 0.f, lam = 0.f;

    for (int kb = 0; kb < NTILE; ++kb) {
        const int kbase = kb * KBLK;
        __syncthreads();
        f32x4 mreg[4];
        {
            const float* mp_ = Msk + (size_t)qg * LSEQ + kbase + 4 * lq;
#pragma unroll
            for (int m = 0; m < 4; ++m)
                mreg[m] = *(const f32x4*)(mp_ + 16 * m);
        }
        {
            const float* Kg = K + hoff + (size_t)kbase * DIM;
            const float* Vg = V + hoff + (size_t)kbase * DIM;
#pragma unroll
            for (int i = 0; i < 4; ++i) {
                const int id = t + 256 * i;
                const int r = id >> 4, c = (id & 15) * 4;
                float4 kv = *(const float4*)(Kg + r * DIM + c);
                float4 vv = *(const float4*)(Vg + r * DIM + c);
                st4bf(&lds_k[r][c], kv);
                lds_v[c + 0][r] = f2bf(vv.x);
                lds_v[c + 1][r] = f2bf(vv.y);
                lds_v[c + 2][r] = f2bf(vv.z);
                lds_v[c + 3][r] = f2bf(vv.w);
            }
        }
        __syncthreads();

        f32x4 S[4];
#pragma unroll
        for (int m = 0; m < 4; ++m) {
            bf16x8 kf0 = *(const bf16x8*)&lds_k[16 * m + lr][8 * lq];
            bf16x8 kf1 = *(const bf16x8*)&lds_k[16 * m + lr][32 + 8 * lq];
            f32x4 z = (f32x4){0.f, 0.f, 0.f, 0.f};
            z = __builtin_amdgcn_mfma_f32_16x16x32_bf16(kf0, qf[0], z, 0, 0, 0);
            z = __builtin_amdgcn_mfma_f32_16x16x32_bf16(kf1, qf[1], z, 0, 0, 0);
            S[m] = z;
        }

        float tm = fmaxf(fmaxf(fmaxf(S[0][0], S[0][1]), fmaxf(S[0][2], S[0][3])),
                         fmaxf(fmaxf(S[1][0], S[1][1]), fmaxf(S[1][2], S[1][3])));
        tm = fmaxf(tm, fmaxf(fmaxf(fmaxf(S[2][0], S[2][1]), fmaxf(S[2][2], S[2][3])),
                             fmaxf(fmaxf(S[3][0], S[3][1]), fmaxf(S[3][2], S[3][3]))));
        tm = fmaxf(tm, __shfl_xor(tm, 16));
        tm = fmaxf(tm, __shfl_xor(tm, 32));
        if (!__all(tm - mrun <= RESCALE_THR)) {
            const float mn = fmaxf(mrun, tm);
            const float al = __builtin_amdgcn_exp2f(mrun - mn);
            mrun = mn;
            lrun *= al; la2 *= al * al; lam *= al;
#pragma unroll
            for (int dt = 0; dt < 4; ++dt) acc[dt] *= al;
        }

        float psum = 0.f, pp2 = 0.f, ppm = 0.f;
        u16 pb[16];
#pragma unroll
        for (int m = 0; m < 4; ++m) {
#pragma unroll
            for (int r = 0; r < 4; ++r) {
                float p = __builtin_amdgcn_exp2f(S[m][r] - mrun);
                psum += p;
                pp2  += p * p;
                ppm  += p * mreg[m][r];
                pb[4 * m + r] = f2bf(p);
            }
        }
        lrun += psum; la2 += pp2; lam += ppm;

        bf16x8 pf[2];
#pragma unroll
        for (int mp = 0; mp < 2; ++mp) {
            union { u16 h[8]; bf16x8 v; } u;
#pragma unroll
            for (int j = 0; j < 4; ++j) { u.h[j] = pb[8 * mp + j]; u.h[4 + j] = pb[8 * mp + 4 + j]; }
            pf[mp] = u.v;
        }
#pragma unroll
        for (int dt = 0; dt < 4; ++dt) {
#pragma unroll
            for (int mp = 0; mp < 2; ++mp) {
                bf16x8 vf = comb64(&lds_v[16 * dt + lr][32 * mp + 4 * lq],
                                   &lds_v[16 * dt + lr][32 * mp + 16 + 4 * lq]);
                acc[dt] = __builtin_amdgcn_mfma_f32_16x16x32_bf16(vf, pf[mp], acc[dt], 0, 0, 0);
            }
        }
    }

#pragma unroll
    for (int off = 16; off <= 32; off <<= 1) {
        lrun += __shfl_xor(lrun, off);
        la2  += __shfl_xor(la2,  off);
        lam  += __shfl_xor(lam,  off);
    }
    const float inv = 1.0f / lrun;
#pragma unroll
    for (int dt = 0; dt < 4; ++dt) {
        float4 o;
        o.x = acc[dt][0] * inv; o.y = acc[dt][1] * inv;
        o.z = acc[dt][2] * inv; o.w = acc[dt][3] * inv;
        *(float4*)(out + hoff + (size_t)qg * DIM + 16 * dt + 4 * lq) = o;
    }
    float part = la2 * inv * inv - 2.0f * lam * inv;
    part = (l < 16) ? part : 0.f;
#pragma unroll
    for (int off = 1; off <= 8; off <<= 1) part += __shfl_xor(part, off);
    if (l == 0) atomicAdd(loss, part);
}

extern "C" void kernel_launch(void* const* d_in, const int* in_sizes, int n_in,
                              void* d_out, int out_size, void* d_ws, size_t ws_size,
                              hipStream_t stream)
{
    const float* Q   = (const float*)d_in[0];
    const float* K   = (const float*)d_in[1];
    const float* V   = (const float*)d_in[2];
    const float* Msk = (const float*)d_in[3];
    float* out  = (float*)d_out;
    float* loss = out + (size_t)NHEAD * LSEQ * DIM;  // element 4194304

    hipMemsetAsync(loss, 0, sizeof(float), stream);

    const size_t packB = (size_t)2 * NHEAD * NTILE * 4096 * sizeof(u16);        // 16 MB
    const size_t oB    = (size_t)KSPL * NHEAD * LSEQ * DIM * sizeof(float);     // 32 MB
    const size_t sB    = (size_t)KSPL * NHEAD * LSEQ * 4 * sizeof(float);       // 2 MB
    const size_t need  = packB + oB + sB;                                       // ~50 MB

    if (d_ws && ws_size >= need) {
        u16* wsK  = (u16*)d_ws;
        u16* wsV  = wsK + (size_t)NHEAD * NTILE * 4096;
        float* wsO = (float*)((char*)d_ws + packB);
        float* wsS = (float*)((char*)d_ws + packB + oB);
        prepack_kernel<<<NHEAD * NTILE, 256, 0, stream>>>(K, V, Msk, wsK, wsV, loss);
        attn_split_kernel<<<NHEAD * (LSEQ / QBLK) * KSPL, 256, 0, stream>>>(
            Q, wsK, wsV, Msk, wsO, wsS);
        combine_kernel<<<NHEAD * (LSEQ / QBLK), 256, 0, stream>>>(wsO, wsS, out, loss);
    } else {
        masksq_kernel<<<256, 256, 0, stream>>>(Msk, loss);
        attn_fallback_kernel<<<NHEAD * (LSEQ / QBLK), 256, 0, stream>>>(Q, K, V, Msk, out, loss);
    }
}

// Round 11
// 149.133 us; speedup vs baseline: 2.0432x; 1.2808x over previous
//
#include <hip/hip_runtime.h>

#define NHEAD 32
#define LSEQ  2048
#define DIM   64
#define QBLK  64
#define KBLK  64
#define NTILE (LSEQ / KBLK)

typedef float  f32x4  __attribute__((ext_vector_type(4)));
typedef __bf16 bf16x8 __attribute__((ext_vector_type(8)));
typedef unsigned short u16;

__device__ __forceinline__ u16 f2bf(float f) {
    return __builtin_bit_cast(u16, (__bf16)f);   // HW RNE convert
}
__device__ __forceinline__ void st4bf(u16* p, float4 v) {
    union { u16 h[4]; uint2 q; } pk;
    pk.h[0] = f2bf(v.x); pk.h[1] = f2bf(v.y);
    pk.h[2] = f2bf(v.z); pk.h[3] = f2bf(v.w);
    *(uint2*)p = pk.q;
}
__device__ __forceinline__ bf16x8 comb64(const u16* a, const u16* b) {
    union { uint2 q[2]; bf16x8 v; } u;
    u.q[0] = *(const uint2*)a;
    u.q[1] = *(const uint2*)b;
    return u.v;
}
// unpack 4 bf16 (uint2) -> f32x4, 2 VALU/elem, no function-boundary arrays
__device__ __forceinline__ f32x4 bfq(uint2 q) {
    f32x4 r;
    r[0] = __builtin_bit_cast(float, q.x << 16);
    r[1] = __builtin_bit_cast(float, q.x & 0xffff0000u);
    r[2] = __builtin_bit_cast(float, q.y << 16);
    r[3] = __builtin_bit_cast(float, q.y & 0xffff0000u);
    return r;
}

// async global->LDS, 16B per lane (HW: wave-uniform LDS base + lane*16)
__device__ __forceinline__ void gl_lds16(const u16* g, u16* l) {
    __builtin_amdgcn_global_load_lds(
        (const __attribute__((address_space(1))) void*)g,
        (__attribute__((address_space(3))) void*)l, 16, 0, 0);
}

// drain own async stages + barrier (no lgkm drain: zero ds_writes in-loop;
// all ds_reads are consumed -> lgkm-waited before the barrier)
#define TILE_SYNC() asm volatile("s_waitcnt vmcnt(0)\n\ts_barrier" ::: "memory")

// 0.125 (1/sqrt(64)) * log2(e): softmax computed in exp2 domain
#define QSCALE 0.18033688011112042f
#define RESCALE_THR 8.0f

// ============================================================================
// Pre-pass: K -> bf16 tiles, V -> V^T bf16 tiles (gload_lds-linear + XOR-
// swizzled layout), mask -> bf16 (halves the dominant L2-miss stream in the
// main kernel; bf16-mask accuracy proven passing in earlier rounds), PLUS the
// mask^2 loss term (fp32 exact, fused with the conversion read).
// ============================================================================
__global__ void prepack_kernel(const float* __restrict__ K,
                               const float* __restrict__ V,
                               const float* __restrict__ Msk,
                               u16* __restrict__ wsK, u16* __restrict__ wsV,
                               u16* __restrict__ wsM,
                               float* __restrict__ loss)
{
    __shared__ float sv[64][65];
    __shared__ float red2[4];
    const int b = blockIdx.x;          // head*NTILE + kb
    const int head = b >> 5, kb = b & 31;
    const int t = threadIdx.x;
    const size_t hoff = (size_t)head * LSEQ * DIM;
    const float* Kg = K + hoff + (size_t)(kb * KBLK) * DIM;
    const float* Vg = V + hoff + (size_t)(kb * KBLK) * DIM;
    u16* outK = wsK + (size_t)b * 4096;
    u16* outV = wsV + (size_t)b * 4096;

#pragma unroll
    for (int i = 0; i < 16; ++i) {
        const int e = t + 256 * i;
        sv[e >> 6][e & 63] = Vg[e];
    }
#pragma unroll
    for (int i = 0; i < 2; ++i) {
        const int c = t + 256 * i;
        const int r = c >> 3, q = c & 7;
        const int d0 = 8 * (q ^ (r & 7));
        float4 a  = *(const float4*)(Kg + r * DIM + d0);
        float4 bb = *(const float4*)(Kg + r * DIM + d0 + 4);
        union { u16 h[8]; uint4 u; } pk;
        pk.h[0]=f2bf(a.x);  pk.h[1]=f2bf(a.y);  pk.h[2]=f2bf(a.z);  pk.h[3]=f2bf(a.w);
        pk.h[4]=f2bf(bb.x); pk.h[5]=f2bf(bb.y); pk.h[6]=f2bf(bb.z); pk.h[7]=f2bf(bb.w);
        *(uint4*)(outK + c * 8) = pk.u;
    }
    __syncthreads();
#pragma unroll
    for (int i = 0; i < 2; ++i) {
        const int c = t + 256 * i;
        const int d = c >> 3, q = c & 7;
        const int cl = q ^ (d & 7);
        const int mp = cl >> 2, lq = cl & 3;
        union { u16 h[8]; uint4 u; } pk;
#pragma unroll
        for (int s = 0; s < 2; ++s) {
            const int k0 = 4 * (8 * mp + 4 * s + lq);
#pragma unroll
            for (int j = 0; j < 4; ++j)
                pk.h[4 * s + j] = f2bf(sv[k0 + j][d]);
        }
        *(uint4*)(outV + c * 8) = pk.u;
    }

    // ---- mask: bf16 convert (coalesced 16B stores) + mask^2 partial, one read ----
    float s = 0.f;
    const float* mbase = Msk + (size_t)b * 4096;
    u16* mout = wsM + (size_t)b * 4096;
#pragma unroll
    for (int i = 0; i < 2; ++i) {
        const int off = i * 2048 + t * 8;
        float4 a  = *(const float4*)(mbase + off);
        float4 bb = *(const float4*)(mbase + off + 4);
        s += a.x * a.x + a.y * a.y + a.z * a.z + a.w * a.w;
        s += bb.x * bb.x + bb.y * bb.y + bb.z * bb.z + bb.w * bb.w;
        union { u16 h[8]; uint4 u; } pk;
        pk.h[0]=f2bf(a.x);  pk.h[1]=f2bf(a.y);  pk.h[2]=f2bf(a.z);  pk.h[3]=f2bf(a.w);
        pk.h[4]=f2bf(bb.x); pk.h[5]=f2bf(bb.y); pk.h[6]=f2bf(bb.z); pk.h[7]=f2bf(bb.w);
        *(uint4*)(mout + off) = pk.u;
    }
#pragma unroll
    for (int off = 1; off <= 32; off <<= 1) s += __shfl_xor(s, off);
    if ((t & 63) == 0) red2[t >> 6] = s;
    __syncthreads();
    if (t == 0)
        atomicAdd(loss, 32.0f * (red2[0] + red2[1] + red2[2] + red2[3]));
}

// ----------------------------------------------------------------------------
// Textual macros (rule #20: no lambda/pointer boundaries for register state).
// ----------------------------------------------------------------------------
#define STAGE(tile, kbuf, vbuf)                                                \
    {                                                                          \
        const u16* gk = srcK + (size_t)(tile) * 4096;                          \
        const u16* gv = srcV + (size_t)(tile) * 4096;                          \
        gl_lds16(gk,        &lds_k[kbuf][t * 8]);                              \
        gl_lds16(gk + 2048, &lds_k[kbuf][t * 8 + 2048]);                       \
        gl_lds16(gv,        &lds_v[vbuf][t * 8]);                              \
        gl_lds16(gv + 2048, &lds_v[vbuf][t * 8 + 2048]);                       \
    }

// bf16 mask: 4x 8B loads (half the bytes of fp32) + in-reg unpack
#define LDMASK(kb_)                                                            \
    {                                                                          \
        const u16* mp_ = wsM + (size_t)qg * LSEQ + (kb_) * KBLK + 4 * lq;      \
        uint2 q0_ = *(const uint2*)(mp_);                                      \
        uint2 q1_ = *(const uint2*)(mp_ + 16);                                 \
        uint2 q2_ = *(const uint2*)(mp_ + 32);                                 \
        uint2 q3_ = *(const uint2*)(mp_ + 48);                                 \
        mM0 = bfq(q0_); mM1 = bfq(q1_); mM2 = bfq(q2_); mM3 = bfq(q3_);        \
    }

#define QK1(kb_, mm, Sdst)                                                     \
    {                                                                          \
        const u16* kro = (kb_) + (16 * (mm) + lr) * 64;                        \
        bf16x8 kf0 = *(const bf16x8*)(kro + ((lq ^ x7) << 3));                 \
        bf16x8 kf1 = *(const bf16x8*)(kro + (((lq + 4) ^ x7) << 3));           \
        f32x4 z = (f32x4){0.f, 0.f, 0.f, 0.f};                                 \
        z = __builtin_amdgcn_mfma_f32_16x16x32_bf16(kf0, qf[0], z, 0, 0, 0);   \
        z = __builtin_amdgcn_mfma_f32_16x16x32_bf16(kf1, qf[1], z, 0, 0, 0);   \
        Sdst = z;                                                              \
    }

// QK for tile -> 4 named S regs (independent of the SMF/PV chain below it)
#define QK(kbuf, SD0, SD1, SD2, SD3)                                           \
    {                                                                          \
        const u16* kb_ = &lds_k[kbuf][0];                                      \
        __builtin_amdgcn_s_setprio(1);                                         \
        QK1(kb_, 0, SD0) QK1(kb_, 1, SD1) QK1(kb_, 2, SD2) QK1(kb_, 3, SD3)    \
        __builtin_amdgcn_s_setprio(0);                                         \
    }

#define SMPART(Sm, Mm, base)                                                   \
    {                                                                          \
        _Pragma("unroll")                                                      \
        for (int r = 0; r < 4; ++r) {                                          \
            float pe = __builtin_amdgcn_exp2f(Sm[r] - mrun);                   \
            psum += pe;                                                        \
            pp2  += pe * pe;                                                   \
            ppm  += pe * Mm[r];                                                \
            pb[(base) + r] = f2bf(pe);                                         \
        }                                                                      \
    }

// softmax-finish of the PREVIOUS tile (VALU only) -> pf0/pf1 + running state
#define SMF(SS0, SS1, SS2, SS3)                                                \
    {                                                                          \
        float tm = fmaxf(fmaxf(fmaxf(SS0[0], SS0[1]), fmaxf(SS0[2], SS0[3])),  \
                         fmaxf(fmaxf(SS1[0], SS1[1]), fmaxf(SS1[2], SS1[3]))); \
        tm = fmaxf(tm, fmaxf(fmaxf(fmaxf(SS2[0], SS2[1]), fmaxf(SS2[2], SS2[3])), \
                             fmaxf(fmaxf(SS3[0], SS3[1]), fmaxf(SS3[2], SS3[3])))); \
        if (!__all(tm - mrun <= RESCALE_THR)) {                                \
            tm = fmaxf(tm, __shfl_xor(tm, 16));                                \
            tm = fmaxf(tm, __shfl_xor(tm, 32));                                \
            const float mn = fmaxf(mrun, tm);                                  \
            const float al = __builtin_amdgcn_exp2f(mrun - mn);                \
            mrun = mn;                                                         \
            lrun *= al; la2 *= al * al; lam *= al;                             \
            _Pragma("unroll")                                                  \
            for (int dt = 0; dt < 4; ++dt) acc[dt] *= al;                      \
        }                                                                      \
        float psum = 0.f, pp2 = 0.f, ppm = 0.f;                                \
        u16 pb[16];                                                            \
        SMPART(SS0, mM0, 0) SMPART(SS1, mM1, 4)                                \
        SMPART(SS2, mM2, 8) SMPART(SS3, mM3, 12)                               \
        lrun += psum; la2 += pp2; lam += ppm;                                  \
        {                                                                      \
            union { u16 h[8]; bf16x8 v; } u;                                   \
            u.h[0] = pb[0]; u.h[1] = pb[1]; u.h[2] = pb[2]; u.h[3] = pb[3];    \
            u.h[4] = pb[4]; u.h[5] = pb[5]; u.h[6] = pb[6]; u.h[7] = pb[7];    \
            pf0 = u.v;                                                         \
        }                                                                      \
        {                                                                      \
            union { u16 h[8]; bf16x8 v; } u;                                   \
            u.h[0] = pb[8];  u.h[1] = pb[9];  u.h[2] = pb[10]; u.h[3] = pb[11];\
            u.h[4] = pb[12]; u.h[5] = pb[13]; u.h[6] = pb[14]; u.h[7] = pb[15];\
            pf1 = u.v;                                                         \
        }                                                                      \
    }

// PV accumulate of the PREVIOUS tile from V buffer vidx (uses pf0/pf1)
#define PV(vidx)                                                               \
    {                                                                          \
        const u16* vb_ = &lds_v[vidx][0];                                      \
        __builtin_amdgcn_s_setprio(1);                                         \
        _Pragma("unroll")                                                      \
        for (int dt = 0; dt < 4; ++dt) {                                       \
            const u16* vro = vb_ + (16 * dt + lr) * 64;                        \
            bf16x8 vfa = *(const bf16x8*)(vro + ((lq ^ x7) << 3));             \
            bf16x8 vfb = *(const bf16x8*)(vro + (((4 + lq) ^ x7) << 3));       \
            acc[dt] = __builtin_amdgcn_mfma_f32_16x16x32_bf16(vfa, pf0, acc[dt], 0, 0, 0); \
            acc[dt] = __builtin_amdgcn_mfma_f32_16x16x32_bf16(vfb, pf1, acc[dt], 0, 0, 0); \
        }                                                                      \
        __builtin_amdgcn_s_setprio(0);                                         \
    }

#define ROT3(x) x = ((x) == 2) ? 0 : ((x) + 1);

// ============================================================================
// Main fused kernel: r7 two-tile software pipeline (best: 131us attn),
// with bf16 mask loads (halves the dominant L2-miss stream).
// ============================================================================
__launch_bounds__(256, 4)
__global__ void attn_fused_kernel(const float* __restrict__ Q,
                                  const u16* __restrict__ wsK,
                                  const u16* __restrict__ wsV,
                                  const u16* __restrict__ wsM,
                                  float* __restrict__ out,
                                  float* __restrict__ loss)
{
    __shared__ __align__(16) u16 lds_k[2][4096];   // 8KB K tile image x2
    __shared__ __align__(16) u16 lds_v[3][4096];   // 8KB V^T tile image x3

    const int t  = threadIdx.x;
    // bijective XCD-chunked swizzle: 1024 blocks, 8 XCDs, 128-block chunks
    const int wg   = ((int)blockIdx.x & 7) * 128 + ((int)blockIdx.x >> 3);
    const int head = wg >> 5;
    const int qb   = wg & 31;
    const int qbase = qb * QBLK;
    const int w  = t >> 6;
    const int l  = t & 63;
    const int lr = l & 15;
    const int lq = l >> 4;
    const int x7 = lr & 7;

    const size_t hoff = (size_t)head * LSEQ * DIM;
    const int qg = qbase + 16 * w + lr;

    // ---- Q fragments, scale folded in (slots c = 32s + 8lq + j) ----
    bf16x8 qf[2];
#pragma unroll
    for (int s = 0; s < 2; ++s) {
        const float* src = Q + hoff + (size_t)qg * DIM + 32 * s + 8 * lq;
        float4 a = *(const float4*)(src);
        float4 b = *(const float4*)(src + 4);
        union { u16 h[8]; bf16x8 v; } u;
        u.h[0] = f2bf(a.x * QSCALE); u.h[1] = f2bf(a.y * QSCALE);
        u.h[2] = f2bf(a.z * QSCALE); u.h[3] = f2bf(a.w * QSCALE);
        u.h[4] = f2bf(b.x * QSCALE); u.h[5] = f2bf(b.y * QSCALE);
        u.h[6] = f2bf(b.z * QSCALE); u.h[7] = f2bf(b.w * QSCALE);
        qf[s] = u.v;
    }

    f32x4 acc[4];
#pragma unroll
    for (int dt = 0; dt < 4; ++dt) acc[dt] = (f32x4){0.f, 0.f, 0.f, 0.f};
    float mrun = -1e30f, lrun = 0.f, la2 = 0.f, lam = 0.f;

    const u16* srcK = wsK + (size_t)(head * NTILE) * 4096 + t * 8;
    const u16* srcV = wsV + (size_t)(head * NTILE) * 4096 + t * 8;

    // pipeline register state: named, spill-proof
    f32x4 S_a0, S_a1, S_a2, S_a3, S_b0, S_b1, S_b2, S_b3;
    f32x4 mM0, mM1, mM2, mM3;
    bf16x8 pf0, pf1;

    // ---- prologue: tile 0 staged+synced, QK(0), tile 1 staged+synced ----
    STAGE(0, 0, 0);
    TILE_SYNC();
    STAGE(1, 1, 1);
    QK(0, S_a0, S_a1, S_a2, S_a3);       // tile 0 scores -> S_a
    TILE_SYNC();

    int vr = 0, vw = 2;

    // ---- periods 1..30 (two per iteration for S/K parity) ----
    for (int kp = 1; kp <= 29; kp += 2) {
        // period kp (odd): QK(kp)->S_b  ||  SMF+PV(kp-1) from S_a
        STAGE(kp + 1, 0, vw);
        LDMASK(kp - 1);                  // consumed in SMF below, hides behind QK
        QK(1, S_b0, S_b1, S_b2, S_b3);
        SMF(S_a0, S_a1, S_a2, S_a3);
        PV(vr);
        TILE_SYNC();
        ROT3(vr); ROT3(vw);

        // period kp+1 (even): QK(kp+1)->S_a  ||  SMF+PV(kp) from S_b
        STAGE(kp + 2, 1, vw);
        LDMASK(kp);
        QK(0, S_a0, S_a1, S_a2, S_a3);
        SMF(S_b0, S_b1, S_b2, S_b3);
        PV(vr);
        TILE_SYNC();
        ROT3(vr); ROT3(vw);
    }

    // ---- period 31: QK(31)->S_b || SMF+PV(30); no further staging ----
    LDMASK(30);
    QK(1, S_b0, S_b1, S_b2, S_b3);
    SMF(S_a0, S_a1, S_a2, S_a3);
    PV(vr);
    ROT3(vr);

    // ---- epilogue period: SMF+PV(31) ----
    LDMASK(31);
    SMF(S_b0, S_b1, S_b2, S_b3);
    PV(vr);

    // ---- reduce per-lane partials across the 4 k-groups ----
#pragma unroll
    for (int off = 16; off <= 32; off <<= 1) {
        lrun += __shfl_xor(lrun, off);
        la2  += __shfl_xor(la2,  off);
        lam  += __shfl_xor(lam,  off);
    }

    const float inv = 1.0f / lrun;

#pragma unroll
    for (int dt = 0; dt < 4; ++dt) {
        float4 o;
        o.x = acc[dt][0] * inv; o.y = acc[dt][1] * inv;
        o.z = acc[dt][2] * inv; o.w = acc[dt][3] * inv;
        *(float4*)(out + hoff + (size_t)qg * DIM + 16 * dt + 4 * lq) = o;
    }

    float part = la2 * inv * inv - 2.0f * lam * inv;
    part = (l < 16) ? part : 0.f;
#pragma unroll
    for (int off = 1; off <= 8; off <<= 1) part += __shfl_xor(part, off);
    if (l == 0) atomicAdd(loss, part);
}

// ============================================================================
// Fallback (proven r3 kernel) + standalone masksq if workspace too small.
// ============================================================================
__global__ void masksq_kernel(const float* __restrict__ Msk, float* __restrict__ loss)
{
    __shared__ float red[4];
    float s = 0.f;
    const size_t n4 = (size_t)LSEQ * LSEQ / 4;
    for (size_t i = (size_t)blockIdx.x * blockDim.x + threadIdx.x; i < n4;
         i += (size_t)gridDim.x * blockDim.x) {
        float4 v = ((const float4*)Msk)[i];
        s += v.x * v.x + v.y * v.y + v.z * v.z + v.w * v.w;
    }
#pragma unroll
    for (int off = 1; off <= 32; off <<= 1) s += __shfl_xor(s, off);
    if ((threadIdx.x & 63) == 0) red[threadIdx.x >> 6] = s;
    __syncthreads();
    if (threadIdx.x == 0) {
        float tot = red[0] + red[1] + red[2] + red[3];
        atomicAdd(loss, 32.0f * tot);
    }
}

__launch_bounds__(256, 4)
__global__ void attn_fallback_kernel(const float* __restrict__ Q,
                                     const float* __restrict__ K,
                                     const float* __restrict__ V,
                                     const float* __restrict__ Msk,
                                     float* __restrict__ out,
                                     float* __restrict__ loss)
{
    __shared__ __align__(16) u16 lds_k[64][72];
    __shared__ __align__(16) u16 lds_v[64][68];

    const int t  = threadIdx.x;
    const int wg   = ((int)blockIdx.x & 7) * 128 + ((int)blockIdx.x >> 3);
    const int head = wg >> 5;
    const int qb   = wg & 31;
    const int qbase = qb * QBLK;
    const int w  = t >> 6;
    const int l  = t & 63;
    const int lr = l & 15;
    const int lq = l >> 4;

    const size_t hoff = (size_t)head * LSEQ * DIM;
    const int qg = qbase + 16 * w + lr;

    bf16x8 qf[2];
#pragma unroll
    for (int s = 0; s < 2; ++s) {
        const float* src = Q + hoff + (size_t)qg * DIM + 32 * s + 8 * lq;
        float4 a = *(const float4*)(src);
        float4 b = *(const float4*)(src + 4);
        union { u16 h[8]; bf16x8 v; } u;
        u.h[0] = f2bf(a.x * QSCALE); u.h[1] = f2bf(a.y * QSCALE);
        u.h[2] = f2bf(a.z * QSCALE); u.h[3] = f2bf(a.w * QSCALE);
        u.h[4] = f2bf(b.x * QSCALE); u.h[5] = f2bf(b.y * QSCALE);
        u.h[6] = f2bf(b.z * QSCALE); u.h[7] = f2bf(b.w * QSCALE);
        qf[s] = u.v;
    }

    f32x4 acc[4];
#pragma unroll
    for (int dt = 0; dt < 4; ++dt) acc[dt] = (f32x4){0.f, 0.f, 0.f, 0.f};
    float mrun = -1e30f, lrun = 0.f, la2 = 0.f, lam = 0.f;

    for (int kb = 0; kb < NTILE; ++kb) {
        const int kbase = kb * KBLK;
        __syncthreads();
        f32x4 mreg[4];
        {
            const float* mp_ = Msk + (size_t)qg * LSEQ + kbase + 4 * lq;
#pragma unroll
            for (int m = 0; m < 4; ++m)
                mreg[m] = *(const f32x4*)(mp_ + 16 * m);
        }
        {
            const float* Kg = K + hoff + (size_t)kbase * DIM;
            const float* Vg = V + hoff + (size_t)kbase * DIM;
#pragma unroll
            for (int i = 0; i < 4; ++i) {
                const int id = t + 256 * i;
                const int r = id >> 4, c = (id & 15) * 4;
                float4 kv = *(const float4*)(Kg + r * DIM + c);
                float4 vv = *(const float4*)(Vg + r * DIM + c);
                st4bf(&lds_k[r][c], kv);
                lds_v[c + 0][r] = f2bf(vv.x);
                lds_v[c + 1][r] = f2bf(vv.y);
                lds_v[c + 2][r] = f2bf(vv.z);
                lds_v[c + 3][r] = f2bf(vv.w);
            }
        }
        __syncthreads();

        f32x4 S[4];
#pragma unroll
        for (int m = 0; m < 4; ++m) {
            bf16x8 kf0 = *(const bf16x8*)&lds_k[16 * m + lr][8 * lq];
            bf16x8 kf1 = *(const bf16x8*)&lds_k[16 * m + lr][32 + 8 * lq];
            f32x4 z = (f32x4){0.f, 0.f, 0.f, 0.f};
            z = __builtin_amdgcn_mfma_f32_16x16x32_bf16(kf0, qf[0], z, 0, 0, 0);
            z = __builtin_amdgcn_mfma_f32_16x16x32_bf16(kf1, qf[1], z, 0, 0, 0);
            S[m] = z;
        }

        float tm = fmaxf(fmaxf(fmaxf(S[0][0], S[0][1]), fmaxf(S[0][2], S[0][3])),
                         fmaxf(fmaxf(S[1][0], S[1][1]), fmaxf(S[1][2], S[1][3])));
        tm = fmaxf(tm, fmaxf(fmaxf(fmaxf(S[2][0], S[2][1]), fmaxf(S[2][2], S[2][3])),
                             fmaxf(fmaxf(S[3][0], S[3][1]), fmaxf(S[3][2], S[3][3]))));
        tm = fmaxf(tm, __shfl_xor(tm, 16));
        tm = fmaxf(tm, __shfl_xor(tm, 32));
        if (!__all(tm - mrun <= RESCALE_THR)) {
            const float mn = fmaxf(mrun, tm);
            const float al = __builtin_amdgcn_exp2f(mrun - mn);
            mrun = mn;
            lrun *= al; la2 *= al * al; lam *= al;
#pragma unroll
            for (int dt = 0; dt < 4; ++dt) acc[dt] *= al;
        }

        float psum = 0.f, pp2 = 0.f, ppm = 0.f;
        u16 pb[16];
#pragma unroll
        for (int m = 0; m < 4; ++m) {
#pragma unroll
            for (int r = 0; r < 4; ++r) {
                float p = __builtin_amdgcn_exp2f(S[m][r] - mrun);
                psum += p;
                pp2  += p * p;
                ppm  += p * mreg[m][r];
                pb[4 * m + r] = f2bf(p);
            }
        }
        lrun += psum; la2 += pp2; lam += ppm;

        bf16x8 pf[2];
#pragma unroll
        for (int mp = 0; mp < 2; ++mp) {
            union { u16 h[8]; bf16x8 v; } u;
#pragma unroll
            for (int j = 0; j < 4; ++j) { u.h[j] = pb[8 * mp + j]; u.h[4 + j] = pb[8 * mp + 4 + j]; }
            pf[mp] = u.v;
        }
#pragma unroll
        for (int dt = 0; dt < 4; ++dt) {
#pragma unroll
            for (int mp = 0; mp < 2; ++mp) {
                bf16x8 vf = comb64(&lds_v[16 * dt + lr][32 * mp + 4 * lq],
                                   &lds_v[16 * dt + lr][32 * mp + 16 + 4 * lq]);
                acc[dt] = __builtin_amdgcn_mfma_f32_16x16x32_bf16(vf, pf[mp], acc[dt], 0, 0, 0);
            }
        }
    }

#pragma unroll
    for (int off = 16; off <= 32; off <<= 1) {
        lrun += __shfl_xor(lrun, off);
        la2  += __shfl_xor(la2,  off);
        lam  += __shfl_xor(lam,  off);
    }
    const float inv = 1.0f / lrun;
#pragma unroll
    for (int dt = 0; dt < 4; ++dt) {
        float4 o;
        o.x = acc[dt][0] * inv; o.y = acc[dt][1] * inv;
        o.z = acc[dt][2] * inv; o.w = acc[dt][3] * inv;
        *(float4*)(out + hoff + (size_t)qg * DIM + 16 * dt + 4 * lq) = o;
    }
    float part = la2 * inv * inv - 2.0f * lam * inv;
    part = (l < 16) ? part : 0.f;
#pragma unroll
    for (int off = 1; off <= 8; off <<= 1) part += __shfl_xor(part, off);
    if (l == 0) atomicAdd(loss, part);
}

extern "C" void kernel_launch(void* const* d_in, const int* in_sizes, int n_in,
                              void* d_out, int out_size, void* d_ws, size_t ws_size,
                              hipStream_t stream)
{
    const float* Q   = (const float*)d_in[0];
    const float* K   = (const float*)d_in[1];
    const float* V   = (const float*)d_in[2];
    const float* Msk = (const float*)d_in[3];
    float* out  = (float*)d_out;
    float* loss = out + (size_t)NHEAD * LSEQ * DIM;  // element 4194304

    hipMemsetAsync(loss, 0, sizeof(float), stream);

    const size_t packB = (size_t)2 * NHEAD * NTILE * 4096 * sizeof(u16);  // 16 MB
    const size_t maskB = (size_t)LSEQ * LSEQ * sizeof(u16);               // 8 MB
    const size_t need  = packB + maskB;                                   // 24 MB

    if (d_ws && ws_size >= need) {
        u16* wsK = (u16*)d_ws;
        u16* wsV = wsK + (size_t)NHEAD * NTILE * 4096;
        u16* wsM = (u16*)((char*)d_ws + packB);
        prepack_kernel<<<NHEAD * NTILE, 256, 0, stream>>>(K, V, Msk, wsK, wsV, wsM, loss);
        attn_fused_kernel<<<NHEAD * (LSEQ / QBLK), 256, 0, stream>>>(Q, wsK, wsV, wsM, out, loss);
    } else {
        masksq_kernel<<<256, 256, 0, stream>>>(Msk, loss);
        attn_fallback_kernel<<<NHEAD * (LSEQ / QBLK), 256, 0, stream>>>(Q, K, V, Msk, out, loss);
    }
}